// Round 8
// baseline (488.159 us; speedup 1.0000x reference)
//
#include <hip/hip_runtime.h>

#define NV 8192
#define FIN 256
#define FOUT 128
#define NSPLIT 8
#define SPLITW 1024   // NV / NSPLIT
#define NW32 256      // NV / 32: u32 words per adj row in bit matrix

typedef __bf16 bf16_t;
typedef __attribute__((ext_vector_type(8))) __bf16 bf16x8;
typedef __attribute__((ext_vector_type(16))) float f32x16;

// ---------------------------------------------------------------------------
// Kernel 0: pack adj (int32 0/1, 268 MB) -> bit matrix (8 MB), contiguous
// streaming reads. (unchanged from r6, passing)
// ---------------------------------------------------------------------------
__global__ __launch_bounds__(256) void pack_kernel(
    const int* __restrict__ adj, unsigned* __restrict__ bits)
{
  const int g0 = (blockIdx.x * 256 + threadIdx.x) * 4;   // first of 4 u32
  unsigned ob[4];
  #pragma unroll
  for (int k = 0; k < 4; k++) {
    const int* src = adj + (size_t)(g0 + k) * 32;
    unsigned b = 0;
    #pragma unroll
    for (int q = 0; q < 8; q++) {
      int4 v = *(const int4*)(src + q * 4);
      b |= (v.x > 0) ? (1u << (q * 4 + 0)) : 0u;
      b |= (v.y > 0) ? (1u << (q * 4 + 1)) : 0u;
      b |= (v.z > 0) ? (1u << (q * 4 + 2)) : 0u;
      b |= (v.w > 0) ? (1u << (q * 4 + 3)) : 0u;
    }
    ob[k] = b;
  }
  uint4 o = make_uint4(ob[0], ob[1], ob[2], ob[3]);
  *(uint4*)(bits + g0) = o;
}

// ---------------------------------------------------------------------------
// Kernel 1: Wh = h @ W (fp32, exact). Stores WhbT (bf16, transposed [F][N])
// and E1=exp(Wh@a1), F1=exp(0.2*Wh@a1), E2=exp(Wh@a2), F2=exp(0.2*Wh@a2):
// exp(leaky(wh1_i+wh2_j)) = max(E1_i*E2_j, F1_i*F2_j).  (unchanged, passing)
// ---------------------------------------------------------------------------
__global__ __launch_bounds__(256) void wh_kernel(
    const float* __restrict__ h, const float* __restrict__ W,
    const float* __restrict__ a,
    bf16_t* __restrict__ WhbT,
    float* __restrict__ E1, float* __restrict__ F1,
    float* __restrict__ E2, float* __restrict__ F2)
{
  __shared__ float As[64][34];    // [k][i] transposed A tile
  __shared__ float Bs[64][128];   // [k][f]
  __shared__ float Cs[32][129];
  __shared__ float red1[32][16];
  __shared__ float red2[32][16];
  const int t  = threadIdx.x;
  const int i0 = blockIdx.x * 32;
  const int c  = t & 15;   // col group: cols c*8 .. c*8+7
  const int r  = t >> 4;   // row group: rows r*2, r*2+1
  float acc0[8], acc1[8];
  #pragma unroll
  for (int j = 0; j < 8; j++) { acc0[j] = 0.f; acc1[j] = 0.f; }

  for (int k0 = 0; k0 < FIN; k0 += 64) {
    { // stage A (32 rows x 64 k), transposed into LDS
      const int ia = t >> 3;          // 0..31
      const int ka = (t & 7) * 8;     // 0..56
      const float* src = h + (size_t)(i0 + ia) * FIN + k0 + ka;
      float4 v0 = *(const float4*)src;
      float4 v1 = *(const float4*)(src + 4);
      As[ka+0][ia]=v0.x; As[ka+1][ia]=v0.y; As[ka+2][ia]=v0.z; As[ka+3][ia]=v0.w;
      As[ka+4][ia]=v1.x; As[ka+5][ia]=v1.y; As[ka+6][ia]=v1.z; As[ka+7][ia]=v1.w;
    }
    { // stage B (64 k x 128 f)
      const int kb = t >> 2;          // 0..63
      const int cb = (t & 3) * 32;
      const float4* src = (const float4*)(W + (size_t)(k0 + kb) * FOUT + cb);
      float4* dst = (float4*)&Bs[kb][cb];
      #pragma unroll
      for (int q = 0; q < 8; q++) dst[q] = src[q];
    }
    __syncthreads();
    #pragma unroll 4
    for (int k = 0; k < 64; k++) {
      float2 av = *(const float2*)&As[k][r*2];
      float b[8];
      *(float4*)&b[0] = *(const float4*)&Bs[k][c*8];
      *(float4*)&b[4] = *(const float4*)&Bs[k][c*8+4];
      #pragma unroll
      for (int j = 0; j < 8; j++) {
        acc0[j] = fmaf(av.x, b[j], acc0[j]);
        acc1[j] = fmaf(av.y, b[j], acc1[j]);
      }
    }
    __syncthreads();
  }

  // epilogue: Cs tile + per-row dots with a1/a2
  float p1a = 0.f, p2a = 0.f, p1b = 0.f, p2b = 0.f;
  #pragma unroll
  for (int j = 0; j < 8; j++) {
    Cs[r*2][c*8+j]   = acc0[j];
    Cs[r*2+1][c*8+j] = acc1[j];
    float w1 = a[c*8+j];
    float w2 = a[FOUT + c*8+j];
    p1a = fmaf(acc0[j], w1, p1a); p2a = fmaf(acc0[j], w2, p2a);
    p1b = fmaf(acc1[j], w1, p1b); p2b = fmaf(acc1[j], w2, p2b);
  }
  red1[r*2][c]   = p1a; red2[r*2][c]   = p2a;
  red1[r*2+1][c] = p1b; red2[r*2+1][c] = p2b;
  __syncthreads();
  if (t < 32) {
    float s = 0.f;
    #pragma unroll
    for (int q = 0; q < 16; q++) s += red1[t][q];
    E1[i0 + t] = __expf(s);
    F1[i0 + t] = __expf(0.2f * s);
  } else if (t < 64) {
    float s = 0.f;
    #pragma unroll
    for (int q = 0; q < 16; q++) s += red2[t-32][q];
    E2[i0 + t - 32] = __expf(s);
    F2[i0 + t - 32] = __expf(0.2f * s);
  }
  { // WhbT store: thread -> (f = t&127, i-halves of 16)
    const int f = t & 127, half = t >> 7;
    union { bf16_t b[16]; uint4 v[2]; } pk;
    #pragma unroll
    for (int q = 0; q < 16; q++) pk.b[q] = (bf16_t)Cs[half*16 + q][f];
    uint4* dst = (uint4*)(WhbT + (size_t)f * NV + i0 + half*16);
    dst[0] = pk.v[0]; dst[1] = pk.v[1];
  }
}

// ---------------------------------------------------------------------------
// Kernel 2: fused masked-softmax attention — ZERO LDS, ZERO barriers.
// Each lane computes its P values DIRECTLY in mfma_f32_32x32x16_bf16
// A-fragment order (lane l: row = l&31, k = (l>>5)*8+q), and loads its
// B fragment directly from L2-resident WhbT (lane l: col = cg*32+(l&31),
// 16 B at WhbT[col*NV + j]). Wave w owns rows i0+w*32..+31 x all 128 feats
// (4 accumulators). No inter-wave communication of any kind: every wave is
// an independent load->compute->MFMA stream, freely pipelined by the
// compiler across chunks. den closes per-lane + one shfl_xor(32).
// Inputs per chunk: bits (uint2, L2), E2/F2 (L1), WhbT frags (L1/L2).
// ---------------------------------------------------------------------------
__global__ __launch_bounds__(256, 2) void attn_kernel(
    const unsigned* __restrict__ abits, const bf16_t* __restrict__ WhbT,
    const float* __restrict__ E1v, const float* __restrict__ F1v,
    const float* __restrict__ E2v, const float* __restrict__ F2v,
    float* __restrict__ nump, float* __restrict__ denp)
{
  const int t     = threadIdx.x;
  const int rb    = blockIdx.x >> 3;   // 0..63
  const int split = blockIdx.x & 7;    // 0..7
  const int i0 = rb * 128;
  const int j0 = split * SPLITW;
  const int lane = t & 63;
  const int w    = t >> 6;             // 0..3: wave owns rows w*32..w*32+31
  const int ml   = lane & 31;
  const int kh   = (lane >> 5) * 8;    // k-offset within 16-wide MFMA step
  const int row  = i0 + w * 32 + ml;   // this lane's P row (A-frag row)
  const float e1 = E1v[row];
  const float f1 = F1v[row];
  f32x16 acc0 = {}, acc1 = {}, acc2 = {}, acc3 = {};
  float den_t = 0.f;

  const unsigned* brow = abits + (size_t)row * NW32 + (j0 >> 5);
  const bf16_t* bcol0 = WhbT + (size_t)(ml)      * NV + j0;
  const bf16_t* bcol1 = WhbT + (size_t)(32 + ml) * NV + j0;
  const bf16_t* bcol2 = WhbT + (size_t)(64 + ml) * NV + j0;
  const bf16_t* bcol3 = WhbT + (size_t)(96 + ml) * NV + j0;

  for (int jc = 0; jc < SPLITW; jc += 64) {
    const uint2 bw = *(const uint2*)(brow + (jc >> 5));  // 64 mask bits
    #pragma unroll
    for (int ks = 0; ks < 4; ks++) {
      const int jj = jc + ks * 16 + kh;          // lane's 8-col j offset
      // softmax factors for the 8 cols (L1-resident, broadcast per half-wave)
      float4 e4a = *(const float4*)(E2v + j0 + jj);
      float4 e4b = *(const float4*)(E2v + j0 + jj + 4);
      float4 f4a = *(const float4*)(F2v + j0 + jj);
      float4 f4b = *(const float4*)(F2v + j0 + jj + 4);
      // mask bits for these 8 cols
      const int bi = ks * 16 + kh;               // 0,8,16,..,56
      const unsigned wd = (bi & 32) ? bw.y : bw.x;
      const unsigned hb = wd >> (bi & 31);       // bits 0..7 valid
      // P fragment, in A-frag register order
      bf16x8 pa;
      float p;
      p = fmaxf(e1*e4a.x, f1*f4a.x); p = (hb &   1u) ? p : 0.f; den_t += p; pa[0] = (bf16_t)p;
      p = fmaxf(e1*e4a.y, f1*f4a.y); p = (hb &   2u) ? p : 0.f; den_t += p; pa[1] = (bf16_t)p;
      p = fmaxf(e1*e4a.z, f1*f4a.z); p = (hb &   4u) ? p : 0.f; den_t += p; pa[2] = (bf16_t)p;
      p = fmaxf(e1*e4a.w, f1*f4a.w); p = (hb &   8u) ? p : 0.f; den_t += p; pa[3] = (bf16_t)p;
      p = fmaxf(e1*e4b.x, f1*f4b.x); p = (hb &  16u) ? p : 0.f; den_t += p; pa[4] = (bf16_t)p;
      p = fmaxf(e1*e4b.y, f1*f4b.y); p = (hb &  32u) ? p : 0.f; den_t += p; pa[5] = (bf16_t)p;
      p = fmaxf(e1*e4b.z, f1*f4b.z); p = (hb &  64u) ? p : 0.f; den_t += p; pa[6] = (bf16_t)p;
      p = fmaxf(e1*e4b.w, f1*f4b.w); p = (hb & 128u) ? p : 0.f; den_t += p; pa[7] = (bf16_t)p;
      // B fragments: direct 16 B loads from L1/L2-resident WhbT
      bf16x8 b0 = *(const bf16x8*)(bcol0 + jj);
      bf16x8 b1 = *(const bf16x8*)(bcol1 + jj);
      bf16x8 b2 = *(const bf16x8*)(bcol2 + jj);
      bf16x8 b3 = *(const bf16x8*)(bcol3 + jj);
      acc0 = __builtin_amdgcn_mfma_f32_32x32x16_bf16(pa, b0, acc0, 0, 0, 0);
      acc1 = __builtin_amdgcn_mfma_f32_32x32x16_bf16(pa, b1, acc1, 0, 0, 0);
      acc2 = __builtin_amdgcn_mfma_f32_32x32x16_bf16(pa, b2, acc2, 0, 0, 0);
      acc3 = __builtin_amdgcn_mfma_f32_32x32x16_bf16(pa, b3, acc3, 0, 0, 0);
    }
  }

  // den: lane l and l^32 hold the two k-halves of row (w*32 + ml)
  const float den_full = den_t + __shfl_xor(den_t, 32);
  if (lane < 32) {
    denp[(size_t)split * NV + row] = den_full;
  }
  // num partial write; C/D layout: col = lane&31, row = (reg&3)+8*(reg>>2)+4*(lane>>5)
  float* base = nump + ((size_t)split * NV + i0) * FOUT;
  const int r4 = 4 * (lane >> 5);
  #pragma unroll
  for (int reg = 0; reg < 16; reg++) {
    const int crow = w * 32 + (reg & 3) + 8 * (reg >> 2) + r4;
    base[(size_t)crow * FOUT + ml]      = acc0[reg];
    base[(size_t)crow * FOUT + ml + 32] = acc1[reg];
    base[(size_t)crow * FOUT + ml + 64] = acc2[reg];
    base[(size_t)crow * FOUT + ml + 96] = acc3[reg];
  }
}

// ---------------------------------------------------------------------------
// Kernel 3: out = elu( (sum_s num_s) / (sum_s den_s) ), 8 splits
// ---------------------------------------------------------------------------
__global__ __launch_bounds__(256) void finalize_kernel(
    const float* __restrict__ nump, const float* __restrict__ denp,
    float* __restrict__ out)
{
  const int gid = blockIdx.x * 256 + threadIdx.x;   // 0 .. 262143
  const int i  = gid >> 5;
  const int f0 = (gid & 31) * 4;
  float den = 0.f;
  #pragma unroll
  for (int sp = 0; sp < NSPLIT; sp++) den += denp[(size_t)sp * NV + i];
  float4 s = make_float4(0.f, 0.f, 0.f, 0.f);
  #pragma unroll
  for (int sp = 0; sp < NSPLIT; sp++) {
    float4 v = *(const float4*)&nump[((size_t)sp * NV + i) * FOUT + f0];
    s.x += v.x; s.y += v.y; s.z += v.z; s.w += v.w;
  }
  const float inv = 1.0f / den;
  float4 r;
  r.x = s.x * inv; r.y = s.y * inv; r.z = s.z * inv; r.w = s.w * inv;
  r.x = r.x > 0.f ? r.x : __expf(r.x) - 1.0f;
  r.y = r.y > 0.f ? r.y : __expf(r.y) - 1.0f;
  r.z = r.z > 0.f ? r.z : __expf(r.z) - 1.0f;
  r.w = r.w > 0.f ? r.w : __expf(r.w) - 1.0f;
  *(float4*)&out[(size_t)i * FOUT + f0] = r;
}

// ---------------------------------------------------------------------------
extern "C" void kernel_launch(void* const* d_in, const int* in_sizes, int n_in,
                              void* d_out, int out_size, void* d_ws, size_t ws_size,
                              hipStream_t stream) {
  const float* h  = (const float*)d_in[0];
  const int*  adj = (const int*)d_in[1];
  const float* W  = (const float*)d_in[2];
  const float* a  = (const float*)d_in[3];
  float* out = (float*)d_out;
  char* ws = (char*)d_ws;
  // workspace layout (~45 MB total):
  bf16_t* WhbT = (bf16_t*)ws;                    // 2 MB
  float* E1   = (float*)(ws + 2097152);          // 32 KB
  float* F1   = (float*)(ws + 2129920);          // 32 KB
  float* E2   = (float*)(ws + 2162688);          // 32 KB
  float* F2   = (float*)(ws + 2195456);          // 32 KB
  float* denp = (float*)(ws + 2228224);          // 256 KB (8 splits)
  float* nump = (float*)(ws + 2490368);          // 32 MB  (8 splits)
  unsigned* AdjBits = (unsigned*)(ws + 2490368 + 33554432);  // 8 MB

  pack_kernel<<<2048, 256, 0, stream>>>(adj, AdjBits);
  wh_kernel<<<256, 256, 0, stream>>>(h, W, a, WhbT, E1, F1, E2, F2);
  attn_kernel<<<512, 256, 0, stream>>>(AdjBits, WhbT, E1, F1, E2, F2, nump, denp);
  finalize_kernel<<<1024, 256, 0, stream>>>(nump, denp, out);
}